// Round 2
// baseline (118.218 us; speedup 1.0000x reference)
//
#include <hip/hip_runtime.h>

#define HH 512
#define WW 512
#define BB 4
#define TILE 32
#define HALO 5
#define LT (TILE + 2 * HALO) /* 42 */
#define SGS 43               /* sg row stride in float4 (pad for banks) */
#define SRS 43               /* r  row stride in floats */
#define PI_F 3.14159265358979323846f

// Depth-aware scatter (splat) bokeh as gather.
// out[b,c,y,x] = sum_disk [r(src)>=dist] g(src) rgb(src,c) / sum_disk [r(src)>=dist] g(src)
// Each thread computes a vertical 1x4 pixel strip; per dj-column the source
// rows for the 4 pixels overlap (ndi+3 loads instead of 4*ndi) -> 2.8x fewer
// LDS reads than 1px/thread.
__global__ __launch_bounds__(256) void Scatter_Rendering_87101936763449_kernel(
    const float* __restrict__ x, const float* __restrict__ lens,
    const float* __restrict__ dk, float* __restrict__ out) {
    __shared__ float4 sg[LT * SGS]; // (s0,s1,s2,g)
    __shared__ float  sr[LT * SRS]; // r

    const int b  = blockIdx.z;
    const int bx = blockIdx.x * TILE;
    const int by = blockIdx.y * TILE;
    const int t  = threadIdx.x;

    const float le = lens[b];
    const float* xb = x + (size_t)b * 4 * HH * WW;

    // Stage 42x42 halo'd tile.
    for (int i = t; i < LT * LT; i += 256) {
        int ly = i / LT, lx = i - ly * LT;
        int gy = by + ly - HALO; gy = gy < 0 ? 0 : (gy > HH - 1 ? HH - 1 : gy);
        int gx = bx + lx - HALO; gx = gx < 0 ? 0 : (gx > WW - 1 ? WW - 1 : gx);
        int gi = gy * WW + gx;
        float d  = xb[3 * HH * WW + gi];
        float r  = fminf(fabsf(d) * le, (float)HALO);
        float g  = 1.0f / (PI_F * r * r + 1.0f);
        sr[ly * SRS + lx] = r;
        sg[ly * SGS + lx] = make_float4(xb[gi] * g, xb[HH * WW + gi] * g,
                                        xb[2 * HH * WW + gi] * g, g);
    }

    // The 14 distinct dist values, taken from the INPUT diskernel (exact
    // floats the reference compares against). Static indices -> registers.
    float distv[26];
#pragma unroll
    for (int a = 0; a <= 5; ++a) {
#pragma unroll
        for (int c = a; c <= 5; ++c) {
            int d2 = a * a + c * c;
            if (d2 <= 25) distv[d2] = dk[(5 + a) * 11 + (5 + c)];
        }
    }

    __syncthreads();

    const int tx   = t & 31;       // column within tile
    const int tyq  = t >> 5;       // quad-row (owns rows tyq*4 .. +3)
    const int yloc = tyq * 4;

    // Active di range per dj for the d2<=25 disk.
    const int DIMIN[11] = {5, 2, 1, 1, 1, 0, 1, 1, 1, 2, 5};
    const int DIMAX[11] = {5, 8, 9, 9, 9, 10, 9, 9, 9, 8, 5};

    float acc[4][4]; // [p][{r,g,b,den}]
#pragma unroll
    for (int p = 0; p < 4; ++p)
#pragma unroll
        for (int c = 0; c < 4; ++c) acc[p][c] = 0.f;

#pragma unroll
    for (int dj = 0; dj < 11; ++dj) {
        const int lo = DIMIN[dj], hi = DIMAX[dj];
        float  rr[14];
        float4 vv[14];
#pragma unroll
        for (int k = 0; k <= 13; ++k) {
            if (k > hi - lo + 3) continue;
            const int row = yloc + lo + k;
            rr[k] = sr[row * SRS + tx + dj];
            vv[k] = sg[row * SGS + tx + dj];
        }
#pragma unroll
        for (int di = 0; di <= 10; ++di) {
            if (di < lo || di > hi) continue;
            const int d2 = (di - 5) * (di - 5) + (dj - 5) * (dj - 5);
            const float dist = distv[d2];
#pragma unroll
            for (int p = 0; p < 4; ++p) {
                const float  r = rr[di - lo + p];
                const float4 v = vv[di - lo + p];
                const float wm = (r >= dist) ? 1.0f : 0.0f;
                acc[p][0] = fmaf(wm, v.x, acc[p][0]);
                acc[p][1] = fmaf(wm, v.y, acc[p][1]);
                acc[p][2] = fmaf(wm, v.z, acc[p][2]);
                acc[p][3] = fmaf(wm, v.w, acc[p][3]);
            }
        }
    }

#pragma unroll
    for (int p = 0; p < 4; ++p) {
        const float inv = 1.0f / acc[p][3];
        const size_t o = (size_t)b * 3 * HH * WW + (size_t)(by + yloc + p) * WW + (bx + tx);
        out[o]               = acc[p][0] * inv;
        out[o + HH * WW]     = acc[p][1] * inv;
        out[o + 2 * HH * WW] = acc[p][2] * inv;
    }
}

extern "C" void kernel_launch(void* const* d_in, const int* in_sizes, int n_in,
                              void* d_out, int out_size, void* d_ws, size_t ws_size,
                              hipStream_t stream) {
    const float* x    = (const float*)d_in[0]; // (4,4,512,512)
    const float* lens = (const float*)d_in[1]; // (4,1)
    const float* dk   = (const float*)d_in[2]; // (11,11)
    float* out = (float*)d_out;                // (4,3,512,512)

    dim3 grid(WW / TILE, HH / TILE, BB);       // 16x16x4 = 1024 blocks
    dim3 block(256);
    hipLaunchKernelGGL(Scatter_Rendering_87101936763449_kernel, grid, block, 0, stream,
                       x, lens, dk, out);
}